// Round 5
// baseline (1377.833 us; speedup 1.0000x reference)
//
#include <hip/hip_runtime.h>

#define TT 4096
#define NB 512
#define NH 10
#define NL 8
#define BPG 4          // batch elements per wave (16 lanes each)
#define KS 16          // timesteps per barrier interval
#define NI (TT/KS + NL - 1)

typedef float v4f __attribute__((ext_vector_type(4)));
typedef float v2f __attribute__((ext_vector_type(2)));
#define LO2(v) __builtin_shufflevector(v, v, 0, 1)
#define HI2(v) __builtin_shufflevector(v, v, 2, 3)

__device__ __forceinline__ v2f pk_fma(v2f a, v2f b, v2f c) {
    v2f d;
    asm("v_pk_fma_f32 %0, %1, %2, %3" : "=v"(d) : "v"(a), "v"(b), "v"(c));
    return d;
}

// ---- DPP lane exchange within each row of 16 lanes (VALU pipe, no LDS) ----
// Semantics (per AMD DPP scan idiom "row_shr:4 bank_mask:0xe"):
//   row_shr:N -> dst lane i gets src lane i-N  (valid for row-lane >= N)
//   row_shl:N -> dst lane i gets src lane i+N  (valid for row-lane < 16-N)
__device__ __forceinline__ float dpp_xor1(float v) {   // quad_perm [1,0,3,2]
    return __int_as_float(__builtin_amdgcn_update_dpp(
        __float_as_int(v), __float_as_int(v), 0xB1, 0xF, 0xF, false));
}
__device__ __forceinline__ float dpp_xor2(float v) {   // quad_perm [2,3,0,1]
    return __int_as_float(__builtin_amdgcn_update_dpp(
        __float_as_int(v), __float_as_int(v), 0x4E, 0xF, 0xF, false));
}
__device__ __forceinline__ float dpp_xor4(float v) {
    // banks 0,2 (row lanes 0-3, 8-11; h&4==0) need lane h+4 -> row_shl:4
    // banks 1,3 (row lanes 4-7,12-15; h&4==4) need lane h-4 -> row_shr:4
    int t = __builtin_amdgcn_update_dpp(
        __float_as_int(v), __float_as_int(v), 0x104, 0xF, 0x5, false); // shl:4 -> banks 0,2
    t = __builtin_amdgcn_update_dpp(
        t, __float_as_int(v), 0x114, 0xF, 0xA, false);                 // shr:4 -> banks 1,3
    return __int_as_float(t);
}
__device__ __forceinline__ float dpp_xor8(float v) {   // row_ror:8 == xor8 within 16
    return __int_as_float(__builtin_amdgcn_update_dpp(
        __float_as_int(v), __float_as_int(v), 0x128, 0xF, 0xF, false));
}

// 8 waves/block (wave = layer), 4 batches/wave (rows of 16 lanes).
// Invariant: register r[j] of lane h holds th of lane h^j,
// maintained by a 19-op DPP butterfly per step. Weights are pre-permuted per
// lane (W[j] = whh[h][h^j]) so the recurrence dot is a flat 16-fma tree.
// LDS carries only the cross-layer handoff (1 write + 3 reads per wave/step),
// double-buffered with ONE barrier per KS steps.
__global__ __launch_bounds__(512, 1)
void rnn_pipe(const float* __restrict__ x, const float* __restrict__ h0,
              const float* __restrict__ w_ih0, const float* __restrict__ w_ih_rest,
              const float* __restrict__ w_hh, const float* __restrict__ b_ih,
              const float* __restrict__ b_hh, const float* __restrict__ w_lin,
              const float* __restrict__ b_lin, float* __restrict__ out)
{
    __shared__ __align__(16) float buf[2][NL][KS][BPG][16];   // 32 KiB

    const int tid  = threadIdx.x;
    const int wv   = tid >> 6;          // layer index
    const int lane = tid & 63;
    const int g    = lane >> 4;
    const int h    = lane & 15;
    const int b    = blockIdx.x * BPG + g;

    const float SC = 2.8853900817779268f;   // 2*log2(e), folded into z

    // ---- per-lane weights ----
    float W[16], wl[16];                 // whh permuted (SC-folded), w_lin permuted
    v2f   wih[5];                        // canonical (SC-folded), layers >= 1
    float w0s = 0.f, bias2 = 0.f;
    const float blin = b_lin[0];

    #pragma unroll
    for (int j = 0; j < 16; ++j) {
        const int src = h ^ j;
        W[j]  = (h < NH && src < NH) ? SC * w_hh[(wv*NH + h)*NH + src] : 0.f;
        wl[j] = (src < NH) ? w_lin[src] : 0.f;
    }
    #pragma unroll
    for (int k = 0; k < 5; ++k) wih[k] = (v2f){0.f, 0.f};
    if (h < NH) {
        bias2 = SC * (b_ih[wv*NH + h] + b_hh[wv*NH + h]);
        if (wv == 0) {
            w0s = SC * w_ih0[h];
        } else {
            const float* ir = w_ih_rest + ((wv-1)*NH + h)*NH;
            #pragma unroll
            for (int k = 0; k < 5; ++k) {
                v2f t = *(const v2f*)(ir + 2*k);
                wih[k] = (v2f){SC * t.x, SC * t.y};
            }
        }
    }

    // ---- state init: r[j] = h0 of unit h^j ----
    const size_t hbase = ((size_t)wv*NB + b)*NH;
    float r[16];
    #pragma unroll
    for (int j = 0; j < 16; ++j)
        r[j] = ((h ^ j) < NH) ? h0[hbase + (h ^ j)] : 0.f;

    const int bpbase = (lane & 48) << 2;     // bpermute base for x broadcast (wv 0)
    float xc = 0.f, xn = 0.f, yst = 0.f;
    if (wv == 0) xn = x[(size_t)b*TT + h];

    for (int i = 0; i < NI; ++i) {
        if ((unsigned)(i - wv) < (unsigned)(TT/KS)) {        // wave-uniform
            const int t0 = (i - wv) * KS;
            const int wr = i & 1, rd = wr ^ 1;

            if (wv == 0) {
                xc = xn;
                const int tn = t0 + KS;
                xn = (tn < TT) ? x[(size_t)b*TT + tn + h] : 0.f;
            }

            #pragma unroll
            for (int k = 0; k < KS; ++k) {
                float zp;
                if (wv == 0) {
                    const float xs = __uint_as_float(__builtin_amdgcn_ds_bpermute(
                        bpbase + (k << 2), __float_as_uint(xc)));
                    zp = fmaf(w0s, xs, bias2);
                } else {
                    const float* ip = &buf[rd][wv-1][k][g][0];
                    const v4f i0 = *(const v4f*)ip;
                    const v4f i1 = *(const v4f*)(ip + 4);
                    const v2f i2 = *(const v2f*)(ip + 8);
                    v2f A = pk_fma(wih[0], LO2(i0), (v2f){bias2, 0.f});
                    v2f Q = pk_fma(wih[1], HI2(i0), (v2f){0.f, 0.f});
                    A = pk_fma(wih[2], LO2(i1), A);
                    Q = pk_fma(wih[3], HI2(i1), Q);
                    A = pk_fma(wih[4], i2, A);
                    zp = (A.x + A.y) + (Q.x + Q.y);
                }
                // z = zp + W . r   (4 chains of 4, then fold)
                float z0 = fmaf(W[0],  r[0],  zp);
                float z1 = W[1]  * r[1];
                float z2 = W[2]  * r[2];
                float z3 = W[3]  * r[3];
                z0 = fmaf(W[4],  r[4],  z0); z1 = fmaf(W[5],  r[5],  z1);
                z2 = fmaf(W[6],  r[6],  z2); z3 = fmaf(W[7],  r[7],  z3);
                z0 = fmaf(W[8],  r[8],  z0); z1 = fmaf(W[9],  r[9],  z1);
                z2 = fmaf(W[10], r[10], z2); z3 = fmaf(W[11], r[11], z3);
                z0 = fmaf(W[12], r[12], z0); z1 = fmaf(W[13], r[13], z1);
                z2 = fmaf(W[14], r[14], z2); z3 = fmaf(W[15], r[15], z3);
                const float z = (z0 + z1) + (z2 + z3);       // pre-scaled by 2*log2e
                const float u = __builtin_amdgcn_exp2f(z);
                const float th = fmaf(-2.f, __builtin_amdgcn_rcpf(u + 1.f), 1.f);

                if (wv < NL-1) buf[wr][wv][k][g][h] = th;    // handoff (b32 write)

                // rebuild r[j] = th[h^j] via DPP butterfly (19 VALU ops)
                r[0] = th;
                r[1] = dpp_xor1(r[0]);
                r[2] = dpp_xor2(r[0]);  r[3] = dpp_xor2(r[1]);
                r[4] = dpp_xor4(r[0]);  r[5] = dpp_xor4(r[1]);
                r[6] = dpp_xor4(r[2]);  r[7] = dpp_xor4(r[3]);
                r[8]  = dpp_xor8(r[0]); r[9]  = dpp_xor8(r[1]);
                r[10] = dpp_xor8(r[2]); r[11] = dpp_xor8(r[3]);
                r[12] = dpp_xor8(r[4]); r[13] = dpp_xor8(r[5]);
                r[14] = dpp_xor8(r[6]); r[15] = dpp_xor8(r[7]);

                if (wv == NL-1) {                             // fused final linear
                    float y0 = fmaf(wl[0],  r[0],  blin);
                    float y1 = wl[1]  * r[1];
                    float y2 = wl[2]  * r[2];
                    float y3 = wl[3]  * r[3];
                    y0 = fmaf(wl[4],  r[4],  y0); y1 = fmaf(wl[5],  r[5],  y1);
                    y2 = fmaf(wl[6],  r[6],  y2); y3 = fmaf(wl[7],  r[7],  y3);
                    y0 = fmaf(wl[8],  r[8],  y0); y1 = fmaf(wl[9],  r[9],  y1);
                    y2 = fmaf(wl[10], r[10], y2); y3 = fmaf(wl[11], r[11], y3);
                    y0 = fmaf(wl[12], r[12], y0); y1 = fmaf(wl[13], r[13], y1);
                    y2 = fmaf(wl[14], r[14], y2); y3 = fmaf(wl[15], r[15], y3);
                    const float y = (y0 + y1) + (y2 + y3);
                    if (h == k) yst = y;
                }
            }

            if (wv == NL-1)
                out[(size_t)b*TT + t0 + h] = yst;             // 16 y's per interval
            if (t0 + KS == TT && h < NH)                      // final hidden state
                out[(size_t)NB*TT + ((size_t)wv*NB + b)*NH + h] = r[0];
        }
        __syncthreads();
    }
}

extern "C" void kernel_launch(void* const* d_in, const int* in_sizes, int n_in,
                              void* d_out, int out_size, void* d_ws, size_t ws_size,
                              hipStream_t stream) {
    const float* x         = (const float*)d_in[0];
    const float* h0        = (const float*)d_in[1];
    const float* w_ih0     = (const float*)d_in[2];
    const float* w_ih_rest = (const float*)d_in[3];
    const float* w_hh      = (const float*)d_in[4];
    const float* b_ih      = (const float*)d_in[5];
    const float* b_hh      = (const float*)d_in[6];
    const float* w_lin     = (const float*)d_in[7];
    const float* b_lin     = (const float*)d_in[8];
    float* out = (float*)d_out;

    rnn_pipe<<<dim3(NB / BPG), dim3(512), 0, stream>>>(
        x, h0, w_ih0, w_ih_rest, w_hh, b_ih, b_hh, w_lin, b_lin, out);
}

// Round 6
// 1044.003 us; speedup vs baseline: 1.3198x; 1.3198x over previous
//
#include <hip/hip_runtime.h>

#define TT 4096
#define NB 512
#define NH 10
#define NL 8
#define BPG 4          // batch elements per wave (16 lanes each)
#define KS 16          // timesteps per barrier interval
#define NI (TT/KS + NL - 1)

typedef float v4f __attribute__((ext_vector_type(4)));
typedef float v2f __attribute__((ext_vector_type(2)));
#define LO2(v) __builtin_shufflevector(v, v, 0, 1)
#define HI2(v) __builtin_shufflevector(v, v, 2, 3)

__device__ __forceinline__ v2f pk_fma(v2f a, v2f b, v2f c) {
    v2f d;
    asm("v_pk_fma_f32 %0, %1, %2, %3" : "=v"(d) : "v"(a), "v"(b), "v"(c));
    return d;
}

// ---- DPP lane exchange within each row of 16 lanes (VALU pipe, no LDS) ----
//   row_shr:N -> dst lane i gets src lane i-N  (valid for row-lane >= N)
//   row_shl:N -> dst lane i gets src lane i+N  (valid for row-lane < 16-N)
__device__ __forceinline__ float dpp_xor1(float v) {   // quad_perm [1,0,3,2]
    return __int_as_float(__builtin_amdgcn_update_dpp(
        __float_as_int(v), __float_as_int(v), 0xB1, 0xF, 0xF, false));
}
__device__ __forceinline__ float dpp_xor2(float v) {   // quad_perm [2,3,0,1]
    return __int_as_float(__builtin_amdgcn_update_dpp(
        __float_as_int(v), __float_as_int(v), 0x4E, 0xF, 0xF, false));
}
__device__ __forceinline__ float dpp_xor4(float v) {
    // banks 0,2 (row lanes 0-3, 8-11; h&4==0) need lane h+4 -> row_shl:4
    // banks 1,3 (row lanes 4-7,12-15; h&4==4) need lane h-4 -> row_shr:4
    int t = __builtin_amdgcn_update_dpp(
        __float_as_int(v), __float_as_int(v), 0x104, 0xF, 0x5, false); // shl:4
    t = __builtin_amdgcn_update_dpp(
        t, __float_as_int(v), 0x114, 0xF, 0xA, false);                 // shr:4
    return __int_as_float(t);
}
__device__ __forceinline__ float dpp_xor8(float v) {   // row_ror:8 == xor8 within 16
    return __int_as_float(__builtin_amdgcn_update_dpp(
        __float_as_int(v), __float_as_int(v), 0x128, 0xF, 0xF, false));
}

// 8 waves/block (wave = layer), 4 batches/wave (rows of 16 lanes).
// Per interval of KS steps: (1) precompute ih-projection p[0..15] from the
// previous layer's LDS tile (latency off the chain); (2) serial recurrence
// with DPP-butterfly broadcast and pre-permuted W (W[j] = whh[h][h^j]);
// (3) wave 7 epilogue: vectorized final linear from its own LDS rows.
// ONE barrier per KS steps.
__global__ __launch_bounds__(512, 1)
void rnn_pipe(const float* __restrict__ x, const float* __restrict__ h0,
              const float* __restrict__ w_ih0, const float* __restrict__ w_ih_rest,
              const float* __restrict__ w_hh, const float* __restrict__ b_ih,
              const float* __restrict__ b_hh, const float* __restrict__ w_lin,
              const float* __restrict__ b_lin, float* __restrict__ out)
{
    __shared__ __align__(16) float buf[2][NL][KS][BPG][16];   // 32 KiB

    const int tid  = threadIdx.x;
    const int wv   = tid >> 6;          // layer index
    const int lane = tid & 63;
    const int g    = lane >> 4;
    const int h    = lane & 15;
    const int b    = blockIdx.x * BPG + g;

    const float SC = 2.8853900817779268f;   // 2*log2(e), folded into z

    // ---- per-lane weights ----
    float W[16];                         // whh permuted (SC-folded)
    v2f   wih[5], wl[5];                 // canonical (wih SC-folded)
    float w0s = 0.f, bias2 = 0.f;
    const float blin = b_lin[0];

    #pragma unroll
    for (int j = 0; j < 16; ++j) {
        const int src = h ^ j;
        W[j] = (h < NH && src < NH) ? SC * w_hh[(wv*NH + h)*NH + src] : 0.f;
    }
    #pragma unroll
    for (int k = 0; k < 5; ++k) { wih[k] = (v2f){0.f, 0.f}; wl[k] = *(const v2f*)(w_lin + 2*k); }
    if (h < NH) {
        bias2 = SC * (b_ih[wv*NH + h] + b_hh[wv*NH + h]);
        if (wv == 0) {
            w0s = SC * w_ih0[h];
        } else {
            const float* ir = w_ih_rest + ((wv-1)*NH + h)*NH;
            #pragma unroll
            for (int k = 0; k < 5; ++k) {
                v2f t = *(const v2f*)(ir + 2*k);
                wih[k] = (v2f){SC * t.x, SC * t.y};
            }
        }
    }

    // ---- state init: r[j] = h0 of unit h^j ----
    const size_t hbase = ((size_t)wv*NB + b)*NH;
    float r[16];
    #pragma unroll
    for (int j = 0; j < 16; ++j)
        r[j] = ((h ^ j) < NH) ? h0[hbase + (h ^ j)] : 0.f;

    const int bpbase = (lane & 48) << 2;     // bpermute base (group-local gather)
    float xc = 0.f, xn = 0.f;
    if (wv == 0) xn = x[(size_t)b*TT + h];

    for (int i = 0; i < NI; ++i) {
        if ((unsigned)(i - wv) < (unsigned)(TT/KS)) {        // wave-uniform
            const int t0 = (i - wv) * KS;
            const int wr = i & 1, rd = wr ^ 1;

            // ---- phase 1: ih-projection p[0..15] (off the serial chain) ----
            float p[KS];
            if (wv == 0) {
                xc = xn;
                const int tn = t0 + KS;
                xn = (tn < TT) ? x[(size_t)b*TT + tn + h] : 0.f;
                #pragma unroll
                for (int k = 0; k < KS; ++k) {
                    const float xs = __uint_as_float(__builtin_amdgcn_ds_bpermute(
                        bpbase + (k << 2), __float_as_uint(xc)));
                    p[k] = fmaf(w0s, xs, bias2);
                }
            } else {
                #pragma unroll
                for (int k = 0; k < KS; ++k) {
                    const float* ip = &buf[rd][wv-1][k][g][0];
                    const v4f i0 = *(const v4f*)ip;
                    const v4f i1 = *(const v4f*)(ip + 4);
                    const v2f i2 = *(const v2f*)(ip + 8);
                    v2f A = pk_fma(wih[0], LO2(i0), (v2f){bias2, 0.f});
                    v2f Q = pk_fma(wih[1], HI2(i0), (v2f){0.f, 0.f});
                    A = pk_fma(wih[2], LO2(i1), A);
                    Q = pk_fma(wih[3], HI2(i1), Q);
                    A = pk_fma(wih[4], i2, A);
                    p[k] = (A.x + A.y) + (Q.x + Q.y);
                }
            }

            // ---- phase 2: serial recurrence (registers + DPP only) ----
            #pragma unroll
            for (int k = 0; k < KS; ++k) {
                float z0 = fmaf(W[0],  r[0],  p[k]);
                float z1 = W[1]  * r[1];
                float z2 = W[2]  * r[2];
                float z3 = W[3]  * r[3];
                z0 = fmaf(W[4],  r[4],  z0); z1 = fmaf(W[5],  r[5],  z1);
                z2 = fmaf(W[6],  r[6],  z2); z3 = fmaf(W[7],  r[7],  z3);
                z0 = fmaf(W[8],  r[8],  z0); z1 = fmaf(W[9],  r[9],  z1);
                z2 = fmaf(W[10], r[10], z2); z3 = fmaf(W[11], r[11], z3);
                z0 = fmaf(W[12], r[12], z0); z1 = fmaf(W[13], r[13], z1);
                z2 = fmaf(W[14], r[14], z2); z3 = fmaf(W[15], r[15], z3);
                const float z = (z0 + z1) + (z2 + z3);       // pre-scaled by 2*log2e
                const float u = __builtin_amdgcn_exp2f(z);
                const float th = fmaf(-2.f, __builtin_amdgcn_rcpf(u + 1.f), 1.f);

                buf[wr][wv][k][g][h] = th;                   // handoff / y-staging

                // rebuild r[j] = th[h^j] via DPP butterfly (19 VALU ops)
                r[0] = th;
                r[1] = dpp_xor1(r[0]);
                r[2] = dpp_xor2(r[0]);  r[3] = dpp_xor2(r[1]);
                r[4] = dpp_xor4(r[0]);  r[5] = dpp_xor4(r[1]);
                r[6] = dpp_xor4(r[2]);  r[7] = dpp_xor4(r[3]);
                r[8]  = dpp_xor8(r[0]); r[9]  = dpp_xor8(r[1]);
                r[10] = dpp_xor8(r[2]); r[11] = dpp_xor8(r[3]);
                r[12] = dpp_xor8(r[4]); r[13] = dpp_xor8(r[5]);
                r[14] = dpp_xor8(r[6]); r[15] = dpp_xor8(r[7]);
            }

            // ---- phase 3: wave-7 epilogue — vectorized y for 16 steps ----
            if (wv == NL-1) {
                const float* yp = &buf[wr][NL-1][h][g][0];   // lane h <-> step h
                const v4f y0 = *(const v4f*)yp;
                const v4f y1 = *(const v4f*)(yp + 4);
                const v2f y2 = *(const v2f*)(yp + 8);
                v2f A = pk_fma(wl[0], LO2(y0), (v2f){blin, 0.f});
                v2f Q = pk_fma(wl[1], HI2(y0), (v2f){0.f, 0.f});
                A = pk_fma(wl[2], LO2(y1), A);
                Q = pk_fma(wl[3], HI2(y1), Q);
                A = pk_fma(wl[4], y2, A);
                out[(size_t)b*TT + t0 + h] = (A.x + A.y) + (Q.x + Q.y);
            }
            if (t0 + KS == TT && h < NH)                     // final hidden state
                out[(size_t)NB*TT + ((size_t)wv*NB + b)*NH + h] = r[0];
        }
        __syncthreads();
    }
}

extern "C" void kernel_launch(void* const* d_in, const int* in_sizes, int n_in,
                              void* d_out, int out_size, void* d_ws, size_t ws_size,
                              hipStream_t stream) {
    const float* x         = (const float*)d_in[0];
    const float* h0        = (const float*)d_in[1];
    const float* w_ih0     = (const float*)d_in[2];
    const float* w_ih_rest = (const float*)d_in[3];
    const float* w_hh      = (const float*)d_in[4];
    const float* b_ih      = (const float*)d_in[5];
    const float* b_hh      = (const float*)d_in[6];
    const float* w_lin     = (const float*)d_in[7];
    const float* b_lin     = (const float*)d_in[8];
    float* out = (float*)d_out;

    rnn_pipe<<<dim3(NB / BPG), dim3(512), 0, stream>>>(
        x, h0, w_ih0, w_ih_rest, w_hh, b_ih, b_hh, w_lin, b_lin, out);
}